// Round 3
// baseline (877.517 us; speedup 1.0000x reference)
//
#include <hip/hip_runtime.h>
#include <math.h>
#include <stdint.h>

typedef __bf16 bf16_t;
typedef __bf16 bf16x8 __attribute__((ext_vector_type(8)));
typedef __bf16 bf16x4 __attribute__((ext_vector_type(4)));
typedef float f32x4 __attribute__((ext_vector_type(4)));
typedef short s16x8 __attribute__((ext_vector_type(8)));

#define TOKS 2048
#define INF 2048
#define JNF 8192
#define ONF 2048

// ---------------- async staging helpers ----------------
// Tile: 128 rows x 32 k bf16, unpadded (row stride 32 elems = 64 B), 8 KB.
// 512 chunks of 16 B. Chunk c: row = c>>2, slot = c&3. Slot s of row holds
// SOURCE k-quad (s ^ ((row>>1)&3)) -> fragment reads are <=2-way bank aliased
// (free, m136); global_load_lds writes are lane-contiguous (conflict-free).

__device__ __forceinline__ void stage_async(const bf16_t* __restrict__ src, size_t ld,
                                            bf16_t* lds, int tid) {
#pragma unroll
  for (int r = 0; r < 2; ++r) {
    int c = r * 256 + tid;
    int row = c >> 2;
    int kq = (c & 3) ^ ((row >> 1) & 3);
    const bf16_t* g = src + (size_t)row * ld + kq * 8;
    bf16_t* l = lds + (size_t)(r * 256 + (tid & 0xC0)) * 8;  // wave-uniform base
    __builtin_amdgcn_global_load_lds((const __attribute__((address_space(1))) void*)g,
                                     (__attribute__((address_space(3))) void*)l,
                                     16, 0, 0);
  }
}

__device__ __forceinline__ bf16x8 frag_ld(const bf16_t* lds, int row, int q) {
  int kq = q ^ ((row >> 1) & 3);
  return *(const bf16x8*)&lds[row * 32 + kq * 8];
}

// ---------------- prep kernels ----------------

__global__ __launch_bounds__(256) void prep_mu_thr(
    const float* __restrict__ med, const float* __restrict__ aad,
    const float* __restrict__ gth, float debiaser,
    float* __restrict__ mu, float* __restrict__ thr, bf16_t* __restrict__ thrb) {
  int gid = blockIdx.x * 256 + threadIdx.x;  // 65536 threads
  if (gid < INF) mu[gid] = med[gid] * debiaser;
  int i = gid & (INF - 1);
  float stdv = aad[i] * debiaser / 2.5066282746310002f;  // sqrt(2*pi)
  float tv = gth[gid] * stdv * 45.254833995939045f;      // sqrt(2048)
  thr[gid] = tv;
  thrb[gid] = (bf16_t)tv;
}

__global__ __launch_bounds__(256) void prep_x(
    const float* __restrict__ x, const float* __restrict__ mu,
    bf16_t* __restrict__ xb, bf16_t* __restrict__ xdb) {
  int idx = (blockIdx.x * 256 + threadIdx.x) * 4;
  f32x4 xv = *(const f32x4*)&x[idx];
  f32x4 muv = *(const f32x4*)&mu[idx & (INF - 1)];
  f32x4 d = xv - muv;
  bf16x4 o, od;
  o[0] = (bf16_t)xv[0]; o[1] = (bf16_t)xv[1];
  o[2] = (bf16_t)xv[2]; o[3] = (bf16_t)xv[3];
  od[0] = (bf16_t)d[0]; od[1] = (bf16_t)d[1];
  od[2] = (bf16_t)d[2]; od[3] = (bf16_t)d[3];
  *(bf16x4*)&xb[idx] = o;
  *(bf16x4*)&xdb[idx] = od;
}

// src [INF, JNF] fp32 -> dst [JNF, INF] bf16
__global__ __launch_bounds__(256) void transpose_cast(
    const float* __restrict__ src, bf16_t* __restrict__ dst) {
  __shared__ float tile[32][33];
  int j0 = blockIdx.x * 32;
  int i0 = blockIdx.y * 32;
  int r = threadIdx.x >> 3;
  int c = (threadIdx.x & 7) * 4;
  f32x4 v = *(const f32x4*)&src[(i0 + r) * JNF + j0 + c];
  tile[r][c] = v[0]; tile[r][c + 1] = v[1]; tile[r][c + 2] = v[2]; tile[r][c + 3] = v[3];
  __syncthreads();
  bf16x4 o;
  o[0] = (bf16_t)tile[c + 0][r];
  o[1] = (bf16_t)tile[c + 1][r];
  o[2] = (bf16_t)tile[c + 2][r];
  o[3] = (bf16_t)tile[c + 3][r];
  *(bf16x4*)&dst[(j0 + r) * INF + i0 + c] = o;
}

__global__ __launch_bounds__(256) void cast_bf16(
    const float* __restrict__ src, bf16_t* __restrict__ dst) {
  int idx = (blockIdx.x * 256 + threadIdx.x) * 8;
  f32x4 a = *(const f32x4*)&src[idx];
  f32x4 b = *(const f32x4*)&src[idx + 4];
  bf16x8 o;
  o[0] = (bf16_t)a[0]; o[1] = (bf16_t)a[1]; o[2] = (bf16_t)a[2]; o[3] = (bf16_t)a[3];
  o[4] = (bf16_t)b[0]; o[5] = (bf16_t)b[1]; o[6] = (bf16_t)b[2]; o[7] = (bf16_t)b[3];
  *(bf16x8*)&dst[idx] = o;
}

__global__ __launch_bounds__(256) void c_init(
    const float* __restrict__ gb, float* __restrict__ c) {
  int j = blockIdx.x * 256 + threadIdx.x;
  c[j] = gb[j];
}

// c[j] += sum_i gw[i,j]*mu[i], split over 8 i-ranges
__global__ __launch_bounds__(256) void c_part(
    const float* __restrict__ gw, const float* __restrict__ mu,
    float* __restrict__ c) {
  int jb = blockIdx.x & 31;
  int ib = blockIdx.x >> 5;
  int j = jb * 256 + threadIdx.x;
  int i0 = ib * 256;
  float s = 0.f;
#pragma unroll 4
  for (int i = 0; i < 256; ++i) s += gw[(size_t)(i0 + i) * JNF + j] * mu[i0 + i];
  atomicAdd(&c[j], s);
}

// exact fp32 mask count (reference semantics): |x - mu| > thr
__global__ __launch_bounds__(256) void count_active(
    const float* __restrict__ x, const float* __restrict__ mu,
    const float* __restrict__ thr,
    float* __restrict__ dense, float* __restrict__ active) {
  int t = blockIdx.x;
  int tid = threadIdx.x;
  int cnt = 0;
  for (int r = 0; r < 8; ++r) {
    int i = (r << 8) + tid;
    float v = fabsf(x[t * INF + i] - mu[i]);
#pragma unroll
    for (int n = 0; n < 32; ++n) cnt += (v > thr[(n << 11) + i]) ? 1 : 0;
  }
  for (int off = 32; off; off >>= 1) cnt += __shfl_down(cnt, off);
  __shared__ int red[4];
  int wv = tid >> 6;
  if ((tid & 63) == 0) red[wv] = cnt;
  __syncthreads();
  if (tid == 0) {
    int tot = red[0] + red[1] + red[2] + red[3];
    active[t] = 256.0f * (float)tot;
    dense[t] = 16777216.0f;
  }
}

// ---------------- fused gate+up GEMM ----------------
// tile 128x128, BK=32, 4 waves (2x2), each wave 64x64 for BOTH g and u.
// Per k-iter per wave: 32 MFMA between one barrier pair; masked-A staging
// in packed-i16 bf16 bit tricks; epilogue writes h = silu(g+c)*(u+ub).

__global__ __launch_bounds__(256) void gateup_gemm(
    const bf16_t* __restrict__ xdb, const bf16_t* __restrict__ thrb,
    const bf16_t* __restrict__ xb,
    const bf16_t* __restrict__ gwT, const bf16_t* __restrict__ upT,
    const float* __restrict__ cj, const float* __restrict__ ub,
    bf16_t* __restrict__ h) {
  __shared__ bf16_t Am[128 * 32];
  __shared__ bf16_t Ax[128 * 32];
  __shared__ bf16_t Bg[128 * 32];
  __shared__ bf16_t Bu[128 * 32];
  int tid = threadIdx.x;
  int t0 = blockIdx.y * 128;
  int j0 = blockIdx.x * 128;
  int n = blockIdx.x >> 1;  // stripe (two 128-col blocks per 256-col stripe)
  int lane = tid & 63;
  int wv = tid >> 6;
  int wr = (wv & 1) * 64;
  int wc = (wv >> 1) * 64;
  int m16 = lane & 15, q = lane >> 4;
  f32x4 ag[4][4] = {};
  f32x4 au[4][4] = {};
  const s16x8 absmask = {0x7FFF, 0x7FFF, 0x7FFF, 0x7FFF, 0x7FFF, 0x7FFF, 0x7FFF, 0x7FFF};
  for (int k0 = 0; k0 < INF; k0 += 32) {
    stage_async(xb + (size_t)t0 * INF + k0, INF, Ax, tid);
    stage_async(gwT + (size_t)j0 * INF + k0, INF, Bg, tid);
    stage_async(upT + (size_t)j0 * INF + k0, INF, Bu, tid);
    // masked A: bf16 bit-compare (positive floats: bit order == value order)
#pragma unroll
    for (int r = 0; r < 2; ++r) {
      int c = r * 256 + tid;
      int row = c >> 2;
      int slot = c & 3;
      int kq = slot ^ ((row >> 1) & 3);
      s16x8 a = *(const s16x8*)&xdb[(size_t)(t0 + row) * INF + k0 + kq * 8];
      s16x8 t = *(const s16x8*)&thrb[n * INF + k0 + kq * 8];
      s16x8 ab = a & absmask;
      s16x8 m = ab > t;  // -1 where |xd| > thr
      s16x8 res = a & m;
      *(s16x8*)&Am[row * 32 + slot * 8] = res;
    }
    __syncthreads();
    bf16x8 amf[4], axf[4], bgf[4], buf[4];
#pragma unroll
    for (int mi = 0; mi < 4; ++mi) {
      amf[mi] = frag_ld(Am, wr + mi * 16 + m16, q);
      axf[mi] = frag_ld(Ax, wr + mi * 16 + m16, q);
    }
#pragma unroll
    for (int ni = 0; ni < 4; ++ni) {
      bgf[ni] = frag_ld(Bg, wc + ni * 16 + m16, q);
      buf[ni] = frag_ld(Bu, wc + ni * 16 + m16, q);
    }
#pragma unroll
    for (int mi = 0; mi < 4; ++mi)
#pragma unroll
      for (int ni = 0; ni < 4; ++ni) {
        ag[mi][ni] = __builtin_amdgcn_mfma_f32_16x16x32_bf16(amf[mi], bgf[ni], ag[mi][ni], 0, 0, 0);
        au[mi][ni] = __builtin_amdgcn_mfma_f32_16x16x32_bf16(axf[mi], buf[ni], au[mi][ni], 0, 0, 0);
      }
    __syncthreads();
  }
#pragma unroll
  for (int mi = 0; mi < 4; ++mi)
#pragma unroll
    for (int ni = 0; ni < 4; ++ni) {
      int col = j0 + wc + ni * 16 + m16;
      float cg = cj[col];
      float cu = ub[col];
#pragma unroll
      for (int r = 0; r < 4; ++r) {
        int row = t0 + wr + mi * 16 + q * 4 + r;
        float gv = ag[mi][ni][r] + cg;
        float uv = au[mi][ni][r] + cu;
        float hv = (gv / (1.f + expf(-gv))) * uv;
        h[(size_t)row * JNF + col] = (bf16_t)hv;
      }
    }
}

// split-K partial: z-th K-chunk of 2048, no bias
__global__ __launch_bounds__(256) void down_gemm(
    const bf16_t* __restrict__ h, const bf16_t* __restrict__ dwb,
    float* __restrict__ part) {
  __shared__ bf16_t Al[128 * 32];
  __shared__ bf16_t Bl[128 * 32];
  int tid = threadIdx.x;
  int t0 = blockIdx.y * 128;
  int o0 = blockIdx.x * 128;
  int kz = blockIdx.z * 2048;
  int lane = tid & 63;
  int wv = tid >> 6;
  int wr = (wv & 1) * 64;
  int wc = (wv >> 1) * 64;
  int m16 = lane & 15, q = lane >> 4;
  f32x4 acc[4][4] = {};
  for (int k0 = kz; k0 < kz + 2048; k0 += 32) {
    stage_async(h + (size_t)t0 * JNF + k0, JNF, Al, tid);
    stage_async(dwb + (size_t)o0 * JNF + k0, JNF, Bl, tid);
    __syncthreads();
    bf16x8 af[4], bf[4];
#pragma unroll
    for (int mi = 0; mi < 4; ++mi) af[mi] = frag_ld(Al, wr + mi * 16 + m16, q);
#pragma unroll
    for (int ni = 0; ni < 4; ++ni) bf[ni] = frag_ld(Bl, wc + ni * 16 + m16, q);
#pragma unroll
    for (int mi = 0; mi < 4; ++mi)
#pragma unroll
      for (int ni = 0; ni < 4; ++ni)
        acc[mi][ni] = __builtin_amdgcn_mfma_f32_16x16x32_bf16(af[mi], bf[ni], acc[mi][ni], 0, 0, 0);
    __syncthreads();
  }
  float* dst = part + (size_t)blockIdx.z * (TOKS * ONF);
#pragma unroll
  for (int mi = 0; mi < 4; ++mi)
#pragma unroll
    for (int ni = 0; ni < 4; ++ni) {
      int col = o0 + wc + ni * 16 + m16;
#pragma unroll
      for (int r = 0; r < 4; ++r) {
        int row = t0 + wr + mi * 16 + q * 4 + r;
        dst[(size_t)row * ONF + col] = acc[mi][ni][r];
      }
    }
}

__global__ __launch_bounds__(256) void down_reduce(
    const float* __restrict__ part, const float* __restrict__ db,
    float* __restrict__ y) {
  int idx = (blockIdx.x * 256 + threadIdx.x) * 4;
  f32x4 a = *(const f32x4*)&part[idx];
  f32x4 b = *(const f32x4*)&part[idx + 4194304];
  f32x4 c = *(const f32x4*)&part[idx + 2 * 4194304];
  f32x4 d = *(const f32x4*)&part[idx + 3 * 4194304];
  f32x4 bias = *(const f32x4*)&db[idx & (ONF - 1)];
  *(f32x4*)&y[idx] = a + b + c + d + bias;
}

// ---------------- launcher ----------------

extern "C" void kernel_launch(void* const* d_in, const int* in_sizes, int n_in,
                              void* d_out, int out_size, void* d_ws, size_t ws_size,
                              hipStream_t stream) {
  (void)in_sizes; (void)n_in; (void)out_size; (void)ws_size;
  const float* x   = (const float*)d_in[0];
  const float* gw  = (const float*)d_in[1];
  const float* gb  = (const float*)d_in[2];
  const float* gth = (const float*)d_in[3];
  const float* med = (const float*)d_in[4];
  const float* aad = (const float*)d_in[5];
  const float* uw  = (const float*)d_in[6];
  const float* ub  = (const float*)d_in[7];
  const float* dw  = (const float*)d_in[8];
  const float* db  = (const float*)d_in[9];

  float* out = (float*)d_out;
  float* y = out;                       // [2048,2048]
  float* dense = out + 4194304;         // [2048]
  float* active = dense + 2048;         // [2048]

  char* ws = (char*)d_ws;
  float*  mu   = (float*)(ws + 0);           //   8 KB
  float*  thr  = (float*)(ws + 8192);        // 256 KB (fp32, exact count)
  bf16_t* thrb = (bf16_t*)(ws + 270336);     // 128 KB (bf16 bits)
  float*  cj   = (float*)(ws + 401408);      //  32 KB
  bf16_t* xb   = (bf16_t*)(ws + 434176);     //   8 MB
  bf16_t* xdb  = (bf16_t*)(ws + 8822784);    //   8 MB
  bf16_t* gwT  = (bf16_t*)(ws + 17211392);   //  32 MB
  bf16_t* upT  = (bf16_t*)(ws + 50765824);   //  32 MB
  bf16_t* dwb  = (bf16_t*)(ws + 84320256);   //  32 MB
  bf16_t* hb   = (bf16_t*)(ws + 117874688);  //  32 MB
  float*  part = (float*)(ws + 151429120);   //  64 MB -> total ~218.5 MB

  float debiaser = (float)(1.0 / (1e-7 + (1.0 - pow(0.99, 1000.0))));

  prep_mu_thr<<<256, 256, 0, stream>>>(med, aad, gth, debiaser, mu, thr, thrb);
  prep_x<<<4096, 256, 0, stream>>>(x, mu, xb, xdb);
  transpose_cast<<<dim3(256, 64), 256, 0, stream>>>(gw, gwT);
  transpose_cast<<<dim3(256, 64), 256, 0, stream>>>(uw, upT);
  cast_bf16<<<8192, 256, 0, stream>>>(dw, dwb);
  c_init<<<32, 256, 0, stream>>>(gb, cj);
  c_part<<<256, 256, 0, stream>>>(gw, mu, cj);
  count_active<<<2048, 256, 0, stream>>>(x, mu, thr, dense, active);
  gateup_gemm<<<dim3(64, 16), 256, 0, stream>>>(xdb, thrb, xb, gwT, upT, cj, ub, hb);
  down_gemm<<<dim3(16, 16, 4), 256, 0, stream>>>(hb, dwb, part);
  down_reduce<<<4096, 256, 0, stream>>>(part, db, y);
}

// Round 4
// 714.426 us; speedup vs baseline: 1.2283x; 1.2283x over previous
//
#include <hip/hip_runtime.h>
#include <math.h>
#include <stdint.h>

typedef __bf16 bf16_t;
typedef __bf16 bf16x8 __attribute__((ext_vector_type(8)));
typedef __bf16 bf16x4 __attribute__((ext_vector_type(4)));
typedef float f32x4 __attribute__((ext_vector_type(4)));
typedef short s16x8 __attribute__((ext_vector_type(8)));

#define TOKS 2048
#define INF 2048
#define JNF 8192
#define ONF 2048

// ---------------- async staging helpers (BK=64) ----------------
// Tile: 128 rows x 64 k bf16, unpadded (row stride 64 elems = 128 B), 16 KB.
// 1024 chunks of 16 B. Chunk c: row = c>>3, slot = c&7; slot holds source
// k-quad (slot ^ (row&7)). Fragment ds_read_b128: 16 lanes/q-group hit 8
// distinct slots -> 2-way bank alias (free, m136). global_load_lds writes
// are lane-contiguous 16B (wave-uniform base + lane*16). [R2: conflicts==0]

__device__ __forceinline__ void stage_async64(const bf16_t* __restrict__ src, size_t ld,
                                              bf16_t* lds, int tid) {
#pragma unroll
  for (int r = 0; r < 4; ++r) {
    int c = r * 256 + tid;
    int row = c >> 3;
    int kq = (c & 7) ^ (row & 7);
    const bf16_t* g = src + (size_t)row * ld + kq * 8;
    bf16_t* l = lds + (size_t)(r * 256 + (tid & 0xC0)) * 8;  // wave-uniform base
    __builtin_amdgcn_global_load_lds((const __attribute__((address_space(1))) void*)g,
                                     (__attribute__((address_space(3))) void*)l,
                                     16, 0, 0);
  }
}

__device__ __forceinline__ bf16x8 frag_ld64(const bf16_t* lds, int row, int kq) {
  int slot = kq ^ (row & 7);
  return *(const bf16x8*)&lds[row * 64 + slot * 8];
}

// ---------------- prep kernels ----------------

__global__ __launch_bounds__(256) void prep_mu_thr(
    const float* __restrict__ med, const float* __restrict__ aad,
    const float* __restrict__ gth, float debiaser,
    float* __restrict__ mu, float* __restrict__ thr, bf16_t* __restrict__ thrb) {
  int gid = blockIdx.x * 256 + threadIdx.x;  // 65536 threads
  if (gid < INF) mu[gid] = med[gid] * debiaser;
  int i = gid & (INF - 1);
  float stdv = aad[i] * debiaser / 2.5066282746310002f;  // sqrt(2*pi)
  float tv = gth[gid] * stdv * 45.254833995939045f;      // sqrt(2048)
  thr[gid] = tv;
  thrb[gid] = (bf16_t)tv;
}

__global__ __launch_bounds__(256) void prep_x(
    const float* __restrict__ x, const float* __restrict__ mu,
    bf16_t* __restrict__ xb, bf16_t* __restrict__ xdb) {
  int idx = (blockIdx.x * 256 + threadIdx.x) * 4;
  f32x4 xv = *(const f32x4*)&x[idx];
  f32x4 muv = *(const f32x4*)&mu[idx & (INF - 1)];
  f32x4 d = xv - muv;
  bf16x4 o, od;
  o[0] = (bf16_t)xv[0]; o[1] = (bf16_t)xv[1];
  o[2] = (bf16_t)xv[2]; o[3] = (bf16_t)xv[3];
  od[0] = (bf16_t)d[0]; od[1] = (bf16_t)d[1];
  od[2] = (bf16_t)d[2]; od[3] = (bf16_t)d[3];
  *(bf16x4*)&xb[idx] = o;
  *(bf16x4*)&xdb[idx] = od;
}

// src [INF, JNF] fp32 -> dst [JNF, INF] bf16
__global__ __launch_bounds__(256) void transpose_cast(
    const float* __restrict__ src, bf16_t* __restrict__ dst) {
  __shared__ float tile[32][33];
  int j0 = blockIdx.x * 32;
  int i0 = blockIdx.y * 32;
  int r = threadIdx.x >> 3;
  int c = (threadIdx.x & 7) * 4;
  f32x4 v = *(const f32x4*)&src[(i0 + r) * JNF + j0 + c];
  tile[r][c] = v[0]; tile[r][c + 1] = v[1]; tile[r][c + 2] = v[2]; tile[r][c + 3] = v[3];
  __syncthreads();
  bf16x4 o;
  o[0] = (bf16_t)tile[c + 0][r];
  o[1] = (bf16_t)tile[c + 1][r];
  o[2] = (bf16_t)tile[c + 2][r];
  o[3] = (bf16_t)tile[c + 3][r];
  *(bf16x4*)&dst[(j0 + r) * INF + i0 + c] = o;
}

__global__ __launch_bounds__(256) void cast_bf16(
    const float* __restrict__ src, bf16_t* __restrict__ dst) {
  int idx = (blockIdx.x * 256 + threadIdx.x) * 8;
  f32x4 a = *(const f32x4*)&src[idx];
  f32x4 b = *(const f32x4*)&src[idx + 4];
  bf16x8 o;
  o[0] = (bf16_t)a[0]; o[1] = (bf16_t)a[1]; o[2] = (bf16_t)a[2]; o[3] = (bf16_t)a[3];
  o[4] = (bf16_t)b[0]; o[5] = (bf16_t)b[1]; o[6] = (bf16_t)b[2]; o[7] = (bf16_t)b[3];
  *(bf16x8*)&dst[idx] = o;
}

__global__ __launch_bounds__(256) void c_init(
    const float* __restrict__ gb, float* __restrict__ c) {
  int j = blockIdx.x * 256 + threadIdx.x;
  c[j] = gb[j];
}

// c[j] += sum_i gw[i,j]*mu[i], split over 8 i-ranges
__global__ __launch_bounds__(256) void c_part(
    const float* __restrict__ gw, const float* __restrict__ mu,
    float* __restrict__ c) {
  int jb = blockIdx.x & 31;
  int ib = blockIdx.x >> 5;
  int j = jb * 256 + threadIdx.x;
  int i0 = ib * 256;
  float s = 0.f;
#pragma unroll 4
  for (int i = 0; i < 256; ++i) s += gw[(size_t)(i0 + i) * JNF + j] * mu[i0 + i];
  atomicAdd(&c[j], s);
}

// exact fp32 mask count (reference semantics): |x - mu| > thr
__global__ __launch_bounds__(256) void count_active(
    const float* __restrict__ x, const float* __restrict__ mu,
    const float* __restrict__ thr,
    float* __restrict__ dense, float* __restrict__ active) {
  int t = blockIdx.x;
  int tid = threadIdx.x;
  int cnt = 0;
  for (int r = 0; r < 8; ++r) {
    int i = (r << 8) + tid;
    float v = fabsf(x[t * INF + i] - mu[i]);
#pragma unroll
    for (int n = 0; n < 32; ++n) cnt += (v > thr[(n << 11) + i]) ? 1 : 0;
  }
  for (int off = 32; off; off >>= 1) cnt += __shfl_down(cnt, off);
  __shared__ int red[4];
  int wv = tid >> 6;
  if ((tid & 63) == 0) red[wv] = cnt;
  __syncthreads();
  if (tid == 0) {
    int tot = red[0] + red[1] + red[2] + red[3];
    active[t] = 256.0f * (float)tot;
    dense[t] = 16777216.0f;
  }
}

// ---------------- GEMM kernels ----------------
// tile 128x128, BK=64, 4 waves (2x2), 4x4 mfma_f32_16x16x32_bf16 per wave,
// 32 MFMA per barrier-pair (2 inner k-steps reusing fragment regs).

__global__ __launch_bounds__(256) void gate_gemm(
    const bf16_t* __restrict__ xdb, const bf16_t* __restrict__ thrb,
    const bf16_t* __restrict__ gwT, const float* __restrict__ cj,
    bf16_t* __restrict__ g) {
  __shared__ bf16_t Al[128 * 64];
  __shared__ bf16_t Bl[128 * 64];
  int tid = threadIdx.x;
  int t0 = blockIdx.y * 128;
  int j0 = blockIdx.x * 128;
  int n = blockIdx.x >> 1;  // stripe (256 cols)
  int lane = tid & 63;
  int wv = tid >> 6;
  int wr = (wv & 1) * 64;
  int wc = (wv >> 1) * 64;
  int m16 = lane & 15, q = lane >> 4;
  f32x4 acc[4][4] = {};
  const s16x8 absmask = {0x7FFF, 0x7FFF, 0x7FFF, 0x7FFF, 0x7FFF, 0x7FFF, 0x7FFF, 0x7FFF};
  for (int k0 = 0; k0 < INF; k0 += 64) {
    stage_async64(gwT + (size_t)j0 * INF + k0, INF, Bl, tid);
    // masked A: bf16 bit-compare (positive floats: bit order == value order)
#pragma unroll
    for (int r = 0; r < 4; ++r) {
      int c = r * 256 + tid;
      int row = c >> 3;
      int slot = c & 7;
      int kq = slot ^ (row & 7);
      s16x8 a = *(const s16x8*)&xdb[(size_t)(t0 + row) * INF + k0 + kq * 8];
      s16x8 t = *(const s16x8*)&thrb[n * INF + k0 + kq * 8];
      s16x8 m = (a & absmask) > t;  // -1 where |xd| > thr
      *(s16x8*)&Al[row * 64 + slot * 8] = a & m;
    }
    __syncthreads();
#pragma unroll
    for (int s = 0; s < 2; ++s) {
      bf16x8 af[4], bf[4];
#pragma unroll
      for (int mi = 0; mi < 4; ++mi) af[mi] = frag_ld64(Al, wr + mi * 16 + m16, s * 4 + q);
#pragma unroll
      for (int ni = 0; ni < 4; ++ni) bf[ni] = frag_ld64(Bl, wc + ni * 16 + m16, s * 4 + q);
#pragma unroll
      for (int mi = 0; mi < 4; ++mi)
#pragma unroll
        for (int ni = 0; ni < 4; ++ni)
          acc[mi][ni] = __builtin_amdgcn_mfma_f32_16x16x32_bf16(af[mi], bf[ni], acc[mi][ni], 0, 0, 0);
    }
    __syncthreads();
  }
#pragma unroll
  for (int mi = 0; mi < 4; ++mi)
#pragma unroll
    for (int ni = 0; ni < 4; ++ni) {
      int col = j0 + wc + ni * 16 + m16;
      float cadd = cj[col];
#pragma unroll
      for (int r = 0; r < 4; ++r) {
        int row = t0 + wr + mi * 16 + q * 4 + r;
        g[(size_t)row * JNF + col] = (bf16_t)(acc[mi][ni][r] + cadd);
      }
    }
}

__global__ __launch_bounds__(256) void up_gemm(
    const bf16_t* __restrict__ xb, const bf16_t* __restrict__ upT,
    const float* __restrict__ ub, const bf16_t* __restrict__ g,
    bf16_t* __restrict__ h) {
  __shared__ bf16_t Al[128 * 64];
  __shared__ bf16_t Bl[128 * 64];
  int tid = threadIdx.x;
  int t0 = blockIdx.y * 128;
  int j0 = blockIdx.x * 128;
  int lane = tid & 63;
  int wv = tid >> 6;
  int wr = (wv & 1) * 64;
  int wc = (wv >> 1) * 64;
  int m16 = lane & 15, q = lane >> 4;
  f32x4 acc[4][4] = {};
  for (int k0 = 0; k0 < INF; k0 += 64) {
    stage_async64(xb + (size_t)t0 * INF + k0, INF, Al, tid);
    stage_async64(upT + (size_t)j0 * INF + k0, INF, Bl, tid);
    __syncthreads();
#pragma unroll
    for (int s = 0; s < 2; ++s) {
      bf16x8 af[4], bf[4];
#pragma unroll
      for (int mi = 0; mi < 4; ++mi) af[mi] = frag_ld64(Al, wr + mi * 16 + m16, s * 4 + q);
#pragma unroll
      for (int ni = 0; ni < 4; ++ni) bf[ni] = frag_ld64(Bl, wc + ni * 16 + m16, s * 4 + q);
#pragma unroll
      for (int mi = 0; mi < 4; ++mi)
#pragma unroll
        for (int ni = 0; ni < 4; ++ni)
          acc[mi][ni] = __builtin_amdgcn_mfma_f32_16x16x32_bf16(af[mi], bf[ni], acc[mi][ni], 0, 0, 0);
    }
    __syncthreads();
  }
#pragma unroll
  for (int mi = 0; mi < 4; ++mi)
#pragma unroll
    for (int ni = 0; ni < 4; ++ni) {
      int col = j0 + wc + ni * 16 + m16;
      float bias = ub[col];
#pragma unroll
      for (int r = 0; r < 4; ++r) {
        int row = t0 + wr + mi * 16 + q * 4 + r;
        float upv = acc[mi][ni][r] + bias;
        float gv = (float)g[(size_t)row * JNF + col];
        float hv = (gv / (1.f + expf(-gv))) * upv;
        h[(size_t)row * JNF + col] = (bf16_t)hv;
      }
    }
}

// split-K partial: z-th K-chunk of 2048, no bias
__global__ __launch_bounds__(256) void down_gemm(
    const bf16_t* __restrict__ h, const bf16_t* __restrict__ dwb,
    float* __restrict__ part) {
  __shared__ bf16_t Al[128 * 64];
  __shared__ bf16_t Bl[128 * 64];
  int tid = threadIdx.x;
  int t0 = blockIdx.y * 128;
  int o0 = blockIdx.x * 128;
  int kz = blockIdx.z * 2048;
  int lane = tid & 63;
  int wv = tid >> 6;
  int wr = (wv & 1) * 64;
  int wc = (wv >> 1) * 64;
  int m16 = lane & 15, q = lane >> 4;
  f32x4 acc[4][4] = {};
  for (int k0 = kz; k0 < kz + 2048; k0 += 64) {
    stage_async64(h + (size_t)t0 * JNF + k0, JNF, Al, tid);
    stage_async64(dwb + (size_t)o0 * JNF + k0, JNF, Bl, tid);
    __syncthreads();
#pragma unroll
    for (int s = 0; s < 2; ++s) {
      bf16x8 af[4], bf[4];
#pragma unroll
      for (int mi = 0; mi < 4; ++mi) af[mi] = frag_ld64(Al, wr + mi * 16 + m16, s * 4 + q);
#pragma unroll
      for (int ni = 0; ni < 4; ++ni) bf[ni] = frag_ld64(Bl, wc + ni * 16 + m16, s * 4 + q);
#pragma unroll
      for (int mi = 0; mi < 4; ++mi)
#pragma unroll
        for (int ni = 0; ni < 4; ++ni)
          acc[mi][ni] = __builtin_amdgcn_mfma_f32_16x16x32_bf16(af[mi], bf[ni], acc[mi][ni], 0, 0, 0);
    }
    __syncthreads();
  }
  float* dst = part + (size_t)blockIdx.z * (TOKS * ONF);
#pragma unroll
  for (int mi = 0; mi < 4; ++mi)
#pragma unroll
    for (int ni = 0; ni < 4; ++ni) {
      int col = o0 + wc + ni * 16 + m16;
#pragma unroll
      for (int r = 0; r < 4; ++r) {
        int row = t0 + wr + mi * 16 + q * 4 + r;
        dst[(size_t)row * ONF + col] = acc[mi][ni][r];
      }
    }
}

__global__ __launch_bounds__(256) void down_reduce(
    const float* __restrict__ part, const float* __restrict__ db,
    float* __restrict__ y) {
  int idx = (blockIdx.x * 256 + threadIdx.x) * 4;
  f32x4 a = *(const f32x4*)&part[idx];
  f32x4 b = *(const f32x4*)&part[idx + 4194304];
  f32x4 c = *(const f32x4*)&part[idx + 2 * 4194304];
  f32x4 d = *(const f32x4*)&part[idx + 3 * 4194304];
  f32x4 bias = *(const f32x4*)&db[idx & (ONF - 1)];
  *(f32x4*)&y[idx] = a + b + c + d + bias;
}

// ---------------- launcher ----------------

extern "C" void kernel_launch(void* const* d_in, const int* in_sizes, int n_in,
                              void* d_out, int out_size, void* d_ws, size_t ws_size,
                              hipStream_t stream) {
  (void)in_sizes; (void)n_in; (void)out_size; (void)ws_size;
  const float* x   = (const float*)d_in[0];
  const float* gw  = (const float*)d_in[1];
  const float* gb  = (const float*)d_in[2];
  const float* gth = (const float*)d_in[3];
  const float* med = (const float*)d_in[4];
  const float* aad = (const float*)d_in[5];
  const float* uw  = (const float*)d_in[6];
  const float* ub  = (const float*)d_in[7];
  const float* dw  = (const float*)d_in[8];
  const float* db  = (const float*)d_in[9];

  float* out = (float*)d_out;
  float* y = out;                       // [2048,2048]
  float* dense = out + 4194304;         // [2048]
  float* active = dense + 2048;         // [2048]

  char* ws = (char*)d_ws;
  float*  mu   = (float*)(ws + 0);           //   8 KB
  float*  thr  = (float*)(ws + 8192);        // 256 KB (fp32, exact count)
  bf16_t* thrb = (bf16_t*)(ws + 270336);     // 128 KB (bf16 bits)
  float*  cj   = (float*)(ws + 401408);      //  32 KB
  bf16_t* xb   = (bf16_t*)(ws + 434176);     //   8 MB
  bf16_t* xdb  = (bf16_t*)(ws + 8822784);    //   8 MB
  bf16_t* gwT  = (bf16_t*)(ws + 17211392);   //  32 MB
  bf16_t* upT  = (bf16_t*)(ws + 50765824);   //  32 MB
  bf16_t* dwb  = (bf16_t*)(ws + 84320256);   //  32 MB
  bf16_t* hb   = (bf16_t*)(ws + 117874688);  //  32 MB
  float*  part = (float*)(ws + 151429120);   //  64 MB -> total ~218.5 MB
  bf16_t* gb16 = (bf16_t*)part;  // alias: g dead before down_gemm writes part

  float debiaser = (float)(1.0 / (1e-7 + (1.0 - pow(0.99, 1000.0))));

  prep_mu_thr<<<256, 256, 0, stream>>>(med, aad, gth, debiaser, mu, thr, thrb);
  prep_x<<<4096, 256, 0, stream>>>(x, mu, xb, xdb);
  transpose_cast<<<dim3(256, 64), 256, 0, stream>>>(gw, gwT);
  transpose_cast<<<dim3(256, 64), 256, 0, stream>>>(uw, upT);
  cast_bf16<<<8192, 256, 0, stream>>>(dw, dwb);
  c_init<<<32, 256, 0, stream>>>(gb, cj);
  c_part<<<256, 256, 0, stream>>>(gw, mu, cj);
  count_active<<<2048, 256, 0, stream>>>(x, mu, thr, dense, active);
  gate_gemm<<<dim3(64, 16), 256, 0, stream>>>(xdb, thrb, gwT, cj, gb16);
  up_gemm<<<dim3(64, 16), 256, 0, stream>>>(xb, upT, ub, gb16, hb);
  down_gemm<<<dim3(16, 16, 4), 256, 0, stream>>>(hb, dwb, part);
  down_reduce<<<4096, 256, 0, stream>>>(part, db, y);
}

// Round 5
// 596.888 us; speedup vs baseline: 1.4702x; 1.1969x over previous
//
#include <hip/hip_runtime.h>
#include <math.h>
#include <stdint.h>

typedef __bf16 bf16_t;
typedef __bf16 bf16x8 __attribute__((ext_vector_type(8)));
typedef __bf16 bf16x4 __attribute__((ext_vector_type(4)));
typedef float f32x4 __attribute__((ext_vector_type(4)));
typedef short s16x8 __attribute__((ext_vector_type(8)));

#define TOKS 2048
#define INF 2048
#define JNF 8192
#define ONF 2048

// ---------------- async staging helpers (BK=64) ----------------
// Tile: 128 rows x 64 k bf16, unpadded (row stride 64 elems = 128 B), 16 KB.
// 1024 chunks of 16 B. Chunk c: row = c>>3, slot = c&7; slot holds source
// k-quad (slot ^ (row&7)). Fragment ds_read_b128: <=2-way bank alias (free,
// m136). global_load_lds writes lane-contiguous 16B. [R2/R4: conflicts==0]

__device__ __forceinline__ void stage_async64(const bf16_t* __restrict__ src, size_t ld,
                                              bf16_t* lds, int tid) {
#pragma unroll
  for (int r = 0; r < 4; ++r) {
    int c = r * 256 + tid;
    int row = c >> 3;
    int kq = (c & 7) ^ (row & 7);
    const bf16_t* g = src + (size_t)row * ld + kq * 8;
    bf16_t* l = lds + (size_t)(r * 256 + (tid & 0xC0)) * 8;  // wave-uniform base
    __builtin_amdgcn_global_load_lds((const __attribute__((address_space(1))) void*)g,
                                     (__attribute__((address_space(3))) void*)l,
                                     16, 0, 0);
  }
}

__device__ __forceinline__ bf16x8 frag_ld64(const bf16_t* lds, int row, int kq) {
  int slot = kq ^ (row & 7);
  return *(const bf16x8*)&lds[row * 64 + slot * 8];
}

// ---------------- prep kernels ----------------

__global__ __launch_bounds__(256) void prep_mu_thr(
    const float* __restrict__ med, const float* __restrict__ aad,
    const float* __restrict__ gth, float debiaser,
    float* __restrict__ mu, float* __restrict__ thr, bf16_t* __restrict__ thrb) {
  int gid = blockIdx.x * 256 + threadIdx.x;  // 65536 threads
  if (gid < INF) mu[gid] = med[gid] * debiaser;
  int i = gid & (INF - 1);
  float stdv = aad[i] * debiaser / 2.5066282746310002f;  // sqrt(2*pi)
  float tv = gth[gid] * stdv * 45.254833995939045f;      // sqrt(2048)
  thr[gid] = tv;
  thrb[gid] = (bf16_t)tv;
}

// One block per token: bf16 casts of x and (x-mu), plus exact fp32 active count.
__global__ __launch_bounds__(256) void prep_x_count(
    const float* __restrict__ x, const float* __restrict__ mu,
    const float* __restrict__ thr,
    bf16_t* __restrict__ xb, bf16_t* __restrict__ xdb,
    float* __restrict__ dense, float* __restrict__ active) {
  int t = blockIdx.x;
  int tid = threadIdx.x;
  int i0 = tid * 8;
  const float* xrow = x + (size_t)t * INF;
  f32x4 x0 = *(const f32x4*)&xrow[i0];
  f32x4 x1 = *(const f32x4*)&xrow[i0 + 4];
  f32x4 m0 = *(const f32x4*)&mu[i0];
  f32x4 m1 = *(const f32x4*)&mu[i0 + 4];
  f32x4 d0 = x0 - m0, d1 = x1 - m1;
  bf16x8 ox, od;
  ox[0] = (bf16_t)x0[0]; ox[1] = (bf16_t)x0[1]; ox[2] = (bf16_t)x0[2]; ox[3] = (bf16_t)x0[3];
  ox[4] = (bf16_t)x1[0]; ox[5] = (bf16_t)x1[1]; ox[6] = (bf16_t)x1[2]; ox[7] = (bf16_t)x1[3];
  od[0] = (bf16_t)d0[0]; od[1] = (bf16_t)d0[1]; od[2] = (bf16_t)d0[2]; od[3] = (bf16_t)d0[3];
  od[4] = (bf16_t)d1[0]; od[5] = (bf16_t)d1[1]; od[6] = (bf16_t)d1[2]; od[7] = (bf16_t)d1[3];
  *(bf16x8*)&xb[(size_t)t * INF + i0] = ox;
  *(bf16x8*)&xdb[(size_t)t * INF + i0] = od;
  f32x4 a0, a1;
  a0[0] = fabsf(d0[0]); a0[1] = fabsf(d0[1]); a0[2] = fabsf(d0[2]); a0[3] = fabsf(d0[3]);
  a1[0] = fabsf(d1[0]); a1[1] = fabsf(d1[1]); a1[2] = fabsf(d1[2]); a1[3] = fabsf(d1[3]);
  int cnt = 0;
#pragma unroll 4
  for (int n = 0; n < 32; ++n) {
    f32x4 t0 = *(const f32x4*)&thr[(n << 11) + i0];
    f32x4 t1 = *(const f32x4*)&thr[(n << 11) + i0 + 4];
    cnt += (a0[0] > t0[0]) + (a0[1] > t0[1]) + (a0[2] > t0[2]) + (a0[3] > t0[3]);
    cnt += (a1[0] > t1[0]) + (a1[1] > t1[1]) + (a1[2] > t1[2]) + (a1[3] > t1[3]);
  }
  for (int off = 32; off; off >>= 1) cnt += __shfl_down(cnt, off);
  __shared__ int red[4];
  int wv = tid >> 6;
  if ((tid & 63) == 0) red[wv] = cnt;
  __syncthreads();
  if (tid == 0) {
    int tot = red[0] + red[1] + red[2] + red[3];
    active[t] = 256.0f * (float)tot;
    dense[t] = 16777216.0f;
  }
}

// src [INF, JNF] fp32 -> dst [JNF, INF] bf16; z selects (gw,uw)
__global__ __launch_bounds__(256) void transpose_cast_dual(
    const float* __restrict__ src0, bf16_t* __restrict__ dst0,
    const float* __restrict__ src1, bf16_t* __restrict__ dst1) {
  const float* src = blockIdx.z ? src1 : src0;
  bf16_t* dst = blockIdx.z ? dst1 : dst0;
  __shared__ float tile[32][33];
  int j0 = blockIdx.x * 32;
  int i0 = blockIdx.y * 32;
  int r = threadIdx.x >> 3;
  int c = (threadIdx.x & 7) * 4;
  f32x4 v = *(const f32x4*)&src[(i0 + r) * JNF + j0 + c];
  tile[r][c] = v[0]; tile[r][c + 1] = v[1]; tile[r][c + 2] = v[2]; tile[r][c + 3] = v[3];
  __syncthreads();
  bf16x4 o;
  o[0] = (bf16_t)tile[c + 0][r];
  o[1] = (bf16_t)tile[c + 1][r];
  o[2] = (bf16_t)tile[c + 2][r];
  o[3] = (bf16_t)tile[c + 3][r];
  *(bf16x4*)&dst[(j0 + r) * INF + i0 + c] = o;
}

__global__ __launch_bounds__(256) void cast_bf16(
    const float* __restrict__ src, bf16_t* __restrict__ dst) {
  int idx = (blockIdx.x * 256 + threadIdx.x) * 8;
  f32x4 a = *(const f32x4*)&src[idx];
  f32x4 b = *(const f32x4*)&src[idx + 4];
  bf16x8 o;
  o[0] = (bf16_t)a[0]; o[1] = (bf16_t)a[1]; o[2] = (bf16_t)a[2]; o[3] = (bf16_t)a[3];
  o[4] = (bf16_t)b[0]; o[5] = (bf16_t)b[1]; o[6] = (bf16_t)b[2]; o[7] = (bf16_t)b[3];
  *(bf16x8*)&dst[idx] = o;
}

// c[j] = gb[j] + sum_i gwT[j,i]*mu[i]; one wave per j-row, no atomics.
__global__ __launch_bounds__(256) void c_from_gwT(
    const bf16_t* __restrict__ gwT, const float* __restrict__ mu,
    const float* __restrict__ gb, float* __restrict__ c) {
  int j = blockIdx.x * 4 + (threadIdx.x >> 6);
  int lane = threadIdx.x & 63;
  float s = 0.f;
#pragma unroll
  for (int it = 0; it < 4; ++it) {
    int i = it * 512 + lane * 8;
    bf16x8 w = *(const bf16x8*)&gwT[(size_t)j * INF + i];
    f32x4 m0 = *(const f32x4*)&mu[i];
    f32x4 m1 = *(const f32x4*)&mu[i + 4];
    s += (float)w[0] * m0[0] + (float)w[1] * m0[1] + (float)w[2] * m0[2] + (float)w[3] * m0[3];
    s += (float)w[4] * m1[0] + (float)w[5] * m1[1] + (float)w[6] * m1[2] + (float)w[7] * m1[3];
  }
  for (int off = 32; off; off >>= 1) s += __shfl_down(s, off);
  if (lane == 0) c[j] = gb[j] + s;
}

// ---------------- GEMM kernels ----------------
// tile 128x128, BK=64, 4 waves (2x2), 4x4 mfma_f32_16x16x32_bf16 per wave,
// 32 MFMA per barrier-pair (2 inner k-steps reusing fragment regs).

__global__ __launch_bounds__(256) void gate_gemm(
    const bf16_t* __restrict__ xdb, const bf16_t* __restrict__ thrb,
    const bf16_t* __restrict__ gwT, const float* __restrict__ cj,
    bf16_t* __restrict__ g) {
  __shared__ bf16_t Al[128 * 64];
  __shared__ bf16_t Bl[128 * 64];
  int tid = threadIdx.x;
  int t0 = blockIdx.y * 128;
  int j0 = blockIdx.x * 128;
  int n = blockIdx.x >> 1;  // stripe (256 cols)
  int lane = tid & 63;
  int wv = tid >> 6;
  int wr = (wv & 1) * 64;
  int wc = (wv >> 1) * 64;
  int m16 = lane & 15, q = lane >> 4;
  f32x4 acc[4][4] = {};
  const s16x8 absmask = {0x7FFF, 0x7FFF, 0x7FFF, 0x7FFF, 0x7FFF, 0x7FFF, 0x7FFF, 0x7FFF};
  for (int k0 = 0; k0 < INF; k0 += 64) {
    stage_async64(gwT + (size_t)j0 * INF + k0, INF, Bl, tid);
    // masked A, branchless packed: active iff |a| > t  <=>  (t - |a|) < 0.
    // m = sign-fill of (t - |a|); res = a & m.  (pk_sub + pk_ashr + 2x and)
#pragma unroll
    for (int r = 0; r < 4; ++r) {
      int c = r * 256 + tid;
      int row = c >> 3;
      int slot = c & 7;
      int kq = slot ^ (row & 7);
      s16x8 a = *(const s16x8*)&xdb[(size_t)(t0 + row) * INF + k0 + kq * 8];
      s16x8 t = *(const s16x8*)&thrb[n * INF + k0 + kq * 8];
      s16x8 m = (s16x8)((t - (a & absmask)) >> 15);
      *(s16x8*)&Al[row * 64 + slot * 8] = a & m;
    }
    __syncthreads();
#pragma unroll
    for (int s = 0; s < 2; ++s) {
      bf16x8 af[4], bf[4];
#pragma unroll
      for (int mi = 0; mi < 4; ++mi) af[mi] = frag_ld64(Al, wr + mi * 16 + m16, s * 4 + q);
#pragma unroll
      for (int ni = 0; ni < 4; ++ni) bf[ni] = frag_ld64(Bl, wc + ni * 16 + m16, s * 4 + q);
#pragma unroll
      for (int mi = 0; mi < 4; ++mi)
#pragma unroll
        for (int ni = 0; ni < 4; ++ni)
          acc[mi][ni] = __builtin_amdgcn_mfma_f32_16x16x32_bf16(af[mi], bf[ni], acc[mi][ni], 0, 0, 0);
    }
    __syncthreads();
  }
#pragma unroll
  for (int mi = 0; mi < 4; ++mi)
#pragma unroll
    for (int ni = 0; ni < 4; ++ni) {
      int col = j0 + wc + ni * 16 + m16;
      float cadd = cj[col];
#pragma unroll
      for (int r = 0; r < 4; ++r) {
        int row = t0 + wr + mi * 16 + q * 4 + r;
        g[(size_t)row * JNF + col] = (bf16_t)(acc[mi][ni][r] + cadd);
      }
    }
}

__global__ __launch_bounds__(256) void up_gemm(
    const bf16_t* __restrict__ xb, const bf16_t* __restrict__ upT,
    const float* __restrict__ ub, const bf16_t* __restrict__ g,
    bf16_t* __restrict__ h) {
  __shared__ bf16_t Al[128 * 64];
  __shared__ bf16_t Bl[128 * 64];
  int tid = threadIdx.x;
  int t0 = blockIdx.y * 128;
  int j0 = blockIdx.x * 128;
  int lane = tid & 63;
  int wv = tid >> 6;
  int wr = (wv & 1) * 64;
  int wc = (wv >> 1) * 64;
  int m16 = lane & 15, q = lane >> 4;
  f32x4 acc[4][4] = {};
  for (int k0 = 0; k0 < INF; k0 += 64) {
    stage_async64(xb + (size_t)t0 * INF + k0, INF, Al, tid);
    stage_async64(upT + (size_t)j0 * INF + k0, INF, Bl, tid);
    __syncthreads();
#pragma unroll
    for (int s = 0; s < 2; ++s) {
      bf16x8 af[4], bf[4];
#pragma unroll
      for (int mi = 0; mi < 4; ++mi) af[mi] = frag_ld64(Al, wr + mi * 16 + m16, s * 4 + q);
#pragma unroll
      for (int ni = 0; ni < 4; ++ni) bf[ni] = frag_ld64(Bl, wc + ni * 16 + m16, s * 4 + q);
#pragma unroll
      for (int mi = 0; mi < 4; ++mi)
#pragma unroll
        for (int ni = 0; ni < 4; ++ni)
          acc[mi][ni] = __builtin_amdgcn_mfma_f32_16x16x32_bf16(af[mi], bf[ni], acc[mi][ni], 0, 0, 0);
    }
    __syncthreads();
  }
#pragma unroll
  for (int mi = 0; mi < 4; ++mi)
#pragma unroll
    for (int ni = 0; ni < 4; ++ni) {
      int col = j0 + wc + ni * 16 + m16;
      float bias = ub[col];
#pragma unroll
      for (int r = 0; r < 4; ++r) {
        int row = t0 + wr + mi * 16 + q * 4 + r;
        float upv = acc[mi][ni][r] + bias;
        float gv = (float)g[(size_t)row * JNF + col];
        float hv = (gv / (1.f + expf(-gv))) * upv;
        h[(size_t)row * JNF + col] = (bf16_t)hv;
      }
    }
}

// split-K partial: z-th K-chunk of 2048, no bias
__global__ __launch_bounds__(256) void down_gemm(
    const bf16_t* __restrict__ h, const bf16_t* __restrict__ dwb,
    float* __restrict__ part) {
  __shared__ bf16_t Al[128 * 64];
  __shared__ bf16_t Bl[128 * 64];
  int tid = threadIdx.x;
  int t0 = blockIdx.y * 128;
  int o0 = blockIdx.x * 128;
  int kz = blockIdx.z * 2048;
  int lane = tid & 63;
  int wv = tid >> 6;
  int wr = (wv & 1) * 64;
  int wc = (wv >> 1) * 64;
  int m16 = lane & 15, q = lane >> 4;
  f32x4 acc[4][4] = {};
  for (int k0 = kz; k0 < kz + 2048; k0 += 64) {
    stage_async64(h + (size_t)t0 * JNF + k0, JNF, Al, tid);
    stage_async64(dwb + (size_t)o0 * JNF + k0, JNF, Bl, tid);
    __syncthreads();
#pragma unroll
    for (int s = 0; s < 2; ++s) {
      bf16x8 af[4], bf[4];
#pragma unroll
      for (int mi = 0; mi < 4; ++mi) af[mi] = frag_ld64(Al, wr + mi * 16 + m16, s * 4 + q);
#pragma unroll
      for (int ni = 0; ni < 4; ++ni) bf[ni] = frag_ld64(Bl, wc + ni * 16 + m16, s * 4 + q);
#pragma unroll
      for (int mi = 0; mi < 4; ++mi)
#pragma unroll
        for (int ni = 0; ni < 4; ++ni)
          acc[mi][ni] = __builtin_amdgcn_mfma_f32_16x16x32_bf16(af[mi], bf[ni], acc[mi][ni], 0, 0, 0);
    }
    __syncthreads();
  }
  float* dst = part + (size_t)blockIdx.z * (TOKS * ONF);
#pragma unroll
  for (int mi = 0; mi < 4; ++mi)
#pragma unroll
    for (int ni = 0; ni < 4; ++ni) {
      int col = o0 + wc + ni * 16 + m16;
#pragma unroll
      for (int r = 0; r < 4; ++r) {
        int row = t0 + wr + mi * 16 + q * 4 + r;
        dst[(size_t)row * ONF + col] = acc[mi][ni][r];
      }
    }
}

__global__ __launch_bounds__(256) void down_reduce(
    const float* __restrict__ part, const float* __restrict__ db,
    float* __restrict__ y) {
  int idx = (blockIdx.x * 256 + threadIdx.x) * 4;
  f32x4 a = *(const f32x4*)&part[idx];
  f32x4 b = *(const f32x4*)&part[idx + 4194304];
  f32x4 c = *(const f32x4*)&part[idx + 2 * 4194304];
  f32x4 d = *(const f32x4*)&part[idx + 3 * 4194304];
  f32x4 bias = *(const f32x4*)&db[idx & (ONF - 1)];
  *(f32x4*)&y[idx] = a + b + c + d + bias;
}

// ---------------- launcher ----------------

extern "C" void kernel_launch(void* const* d_in, const int* in_sizes, int n_in,
                              void* d_out, int out_size, void* d_ws, size_t ws_size,
                              hipStream_t stream) {
  (void)in_sizes; (void)n_in; (void)out_size; (void)ws_size;
  const float* x   = (const float*)d_in[0];
  const float* gw  = (const float*)d_in[1];
  const float* gb  = (const float*)d_in[2];
  const float* gth = (const float*)d_in[3];
  const float* med = (const float*)d_in[4];
  const float* aad = (const float*)d_in[5];
  const float* uw  = (const float*)d_in[6];
  const float* ub  = (const float*)d_in[7];
  const float* dw  = (const float*)d_in[8];
  const float* db  = (const float*)d_in[9];

  float* out = (float*)d_out;
  float* y = out;                       // [2048,2048]
  float* dense = out + 4194304;         // [2048]
  float* active = dense + 2048;         // [2048]

  char* ws = (char*)d_ws;
  float*  mu   = (float*)(ws + 0);           //   8 KB
  float*  thr  = (float*)(ws + 8192);        // 256 KB (fp32, exact count)
  bf16_t* thrb = (bf16_t*)(ws + 270336);     // 128 KB (bf16 bits)
  float*  cj   = (float*)(ws + 401408);      //  32 KB
  bf16_t* xb   = (bf16_t*)(ws + 434176);     //   8 MB
  bf16_t* xdb  = (bf16_t*)(ws + 8822784);    //   8 MB
  bf16_t* gwT  = (bf16_t*)(ws + 17211392);   //  32 MB
  bf16_t* upT  = (bf16_t*)(ws + 50765824);   //  32 MB
  bf16_t* dwb  = (bf16_t*)(ws + 84320256);   //  32 MB
  bf16_t* hb   = (bf16_t*)(ws + 117874688);  //  32 MB
  float*  part = (float*)(ws + 151429120);   //  64 MB -> total ~218.5 MB
  bf16_t* gb16 = (bf16_t*)part;  // alias: g dead before down_gemm writes part

  float debiaser = (float)(1.0 / (1e-7 + (1.0 - pow(0.99, 1000.0))));

  prep_mu_thr<<<256, 256, 0, stream>>>(med, aad, gth, debiaser, mu, thr, thrb);
  prep_x_count<<<2048, 256, 0, stream>>>(x, mu, thr, xb, xdb, dense, active);
  transpose_cast_dual<<<dim3(256, 64, 2), 256, 0, stream>>>(gw, gwT, uw, upT);
  cast_bf16<<<8192, 256, 0, stream>>>(dw, dwb);
  c_from_gwT<<<2048, 256, 0, stream>>>(gwT, mu, gb, cj);
  gate_gemm<<<dim3(64, 16), 256, 0, stream>>>(xdb, thrb, gwT, cj, gb16);
  up_gemm<<<dim3(64, 16), 256, 0, stream>>>(xb, upT, ub, gb16, hb);
  down_gemm<<<dim3(16, 16, 4), 256, 0, stream>>>(hb, dwb, part);
  down_reduce<<<4096, 256, 0, stream>>>(part, db, y);
}

// Round 6
// 547.180 us; speedup vs baseline: 1.6037x; 1.0908x over previous
//
#include <hip/hip_runtime.h>
#include <math.h>
#include <stdint.h>

typedef __bf16 bf16_t;
typedef __bf16 bf16x8 __attribute__((ext_vector_type(8)));
typedef __bf16 bf16x4 __attribute__((ext_vector_type(4)));
typedef float f32x4 __attribute__((ext_vector_type(4)));
typedef short s16x8 __attribute__((ext_vector_type(8)));

#define TOKS 2048
#define INF 2048
#define JNF 8192
#define ONF 2048

// ---------------- async staging helpers (BK=64) ----------------
// Tile: ROWS x 64 k bf16, unpadded (row stride 64 elems = 128 B).
// Chunks of 16 B; chunk c: row = c>>3, slot = c&7; slot holds source
// k-quad (slot ^ (row&7)). Fragment ds_read_b128: <=2-way bank alias (free,
// m136). global_load_lds writes lane-contiguous 16B. [R2/R4/R5: conflicts==0]

template <int ROWS, int NT>
__device__ __forceinline__ void stage_async_t(const bf16_t* __restrict__ src, size_t ld,
                                              bf16_t* lds, int tid) {
  constexpr int IT = ROWS * 8 / NT;
#pragma unroll
  for (int r = 0; r < IT; ++r) {
    int c = r * NT + tid;
    int row = c >> 3;
    int kq = (c & 7) ^ (row & 7);
    const bf16_t* g = src + (size_t)row * ld + kq * 8;
    bf16_t* l = lds + (size_t)(r * NT + (tid & ~63)) * 8;  // wave-uniform base
    __builtin_amdgcn_global_load_lds((const __attribute__((address_space(1))) void*)g,
                                     (__attribute__((address_space(3))) void*)l,
                                     16, 0, 0);
  }
}

__device__ __forceinline__ bf16x8 frag_ld64(const bf16_t* lds, int row, int kq) {
  int slot = kq ^ (row & 7);
  return *(const bf16x8*)&lds[row * 64 + slot * 8];
}

// ---------------- prep kernels ----------------

__global__ __launch_bounds__(256) void prep_mu_thr(
    const float* __restrict__ med, const float* __restrict__ aad,
    const float* __restrict__ gth, float debiaser,
    float* __restrict__ mu, float* __restrict__ thr, bf16_t* __restrict__ thrb) {
  int gid = blockIdx.x * 256 + threadIdx.x;  // 65536 threads
  if (gid < INF) mu[gid] = med[gid] * debiaser;
  int i = gid & (INF - 1);
  float stdv = aad[i] * debiaser / 2.5066282746310002f;  // sqrt(2*pi)
  float tv = gth[gid] * stdv * 45.254833995939045f;      // sqrt(2048)
  thr[gid] = tv;
  thrb[gid] = (bf16_t)tv;
}

// One block per token: bf16 casts of x and (x-mu), plus exact fp32 active count.
__global__ __launch_bounds__(256) void prep_x_count(
    const float* __restrict__ x, const float* __restrict__ mu,
    const float* __restrict__ thr,
    bf16_t* __restrict__ xb, bf16_t* __restrict__ xdb,
    float* __restrict__ dense, float* __restrict__ active) {
  int t = blockIdx.x;
  int tid = threadIdx.x;
  int i0 = tid * 8;
  const float* xrow = x + (size_t)t * INF;
  f32x4 x0 = *(const f32x4*)&xrow[i0];
  f32x4 x1 = *(const f32x4*)&xrow[i0 + 4];
  f32x4 m0 = *(const f32x4*)&mu[i0];
  f32x4 m1 = *(const f32x4*)&mu[i0 + 4];
  f32x4 d0 = x0 - m0, d1 = x1 - m1;
  bf16x8 ox, od;
  ox[0] = (bf16_t)x0[0]; ox[1] = (bf16_t)x0[1]; ox[2] = (bf16_t)x0[2]; ox[3] = (bf16_t)x0[3];
  ox[4] = (bf16_t)x1[0]; ox[5] = (bf16_t)x1[1]; ox[6] = (bf16_t)x1[2]; ox[7] = (bf16_t)x1[3];
  od[0] = (bf16_t)d0[0]; od[1] = (bf16_t)d0[1]; od[2] = (bf16_t)d0[2]; od[3] = (bf16_t)d0[3];
  od[4] = (bf16_t)d1[0]; od[5] = (bf16_t)d1[1]; od[6] = (bf16_t)d1[2]; od[7] = (bf16_t)d1[3];
  *(bf16x8*)&xb[(size_t)t * INF + i0] = ox;
  *(bf16x8*)&xdb[(size_t)t * INF + i0] = od;
  f32x4 a0, a1;
  a0[0] = fabsf(d0[0]); a0[1] = fabsf(d0[1]); a0[2] = fabsf(d0[2]); a0[3] = fabsf(d0[3]);
  a1[0] = fabsf(d1[0]); a1[1] = fabsf(d1[1]); a1[2] = fabsf(d1[2]); a1[3] = fabsf(d1[3]);
  int cnt = 0;
#pragma unroll 4
  for (int n = 0; n < 32; ++n) {
    f32x4 t0 = *(const f32x4*)&thr[(n << 11) + i0];
    f32x4 t1 = *(const f32x4*)&thr[(n << 11) + i0 + 4];
    cnt += (a0[0] > t0[0]) + (a0[1] > t0[1]) + (a0[2] > t0[2]) + (a0[3] > t0[3]);
    cnt += (a1[0] > t1[0]) + (a1[1] > t1[1]) + (a1[2] > t1[2]) + (a1[3] > t1[3]);
  }
  for (int off = 32; off; off >>= 1) cnt += __shfl_down(cnt, off);
  __shared__ int red[4];
  int wv = tid >> 6;
  if ((tid & 63) == 0) red[wv] = cnt;
  __syncthreads();
  if (tid == 0) {
    int tot = red[0] + red[1] + red[2] + red[3];
    active[t] = 256.0f * (float)tot;
    dense[t] = 16777216.0f;
  }
}

// src [INF, JNF] fp32 -> dst [JNF, INF] bf16; z selects (gw,uw)
__global__ __launch_bounds__(256) void transpose_cast_dual(
    const float* __restrict__ src0, bf16_t* __restrict__ dst0,
    const float* __restrict__ src1, bf16_t* __restrict__ dst1) {
  const float* src = blockIdx.z ? src1 : src0;
  bf16_t* dst = blockIdx.z ? dst1 : dst0;
  __shared__ float tile[32][33];
  int j0 = blockIdx.x * 32;
  int i0 = blockIdx.y * 32;
  int r = threadIdx.x >> 3;
  int c = (threadIdx.x & 7) * 4;
  f32x4 v = *(const f32x4*)&src[(i0 + r) * JNF + j0 + c];
  tile[r][c] = v[0]; tile[r][c + 1] = v[1]; tile[r][c + 2] = v[2]; tile[r][c + 3] = v[3];
  __syncthreads();
  bf16x4 o;
  o[0] = (bf16_t)tile[c + 0][r];
  o[1] = (bf16_t)tile[c + 1][r];
  o[2] = (bf16_t)tile[c + 2][r];
  o[3] = (bf16_t)tile[c + 3][r];
  *(bf16x4*)&dst[(j0 + r) * INF + i0 + c] = o;
}

__global__ __launch_bounds__(256) void cast_bf16(
    const float* __restrict__ src, bf16_t* __restrict__ dst) {
  int idx = (blockIdx.x * 256 + threadIdx.x) * 8;
  f32x4 a = *(const f32x4*)&src[idx];
  f32x4 b = *(const f32x4*)&src[idx + 4];
  bf16x8 o;
  o[0] = (bf16_t)a[0]; o[1] = (bf16_t)a[1]; o[2] = (bf16_t)a[2]; o[3] = (bf16_t)a[3];
  o[4] = (bf16_t)b[0]; o[5] = (bf16_t)b[1]; o[6] = (bf16_t)b[2]; o[7] = (bf16_t)b[3];
  *(bf16x8*)&dst[idx] = o;
}

// c[j] = gb[j] + sum_i gwT[j,i]*mu[i]; one wave per j-row, no atomics.
__global__ __launch_bounds__(256) void c_from_gwT(
    const bf16_t* __restrict__ gwT, const float* __restrict__ mu,
    const float* __restrict__ gb, float* __restrict__ c) {
  int j = blockIdx.x * 4 + (threadIdx.x >> 6);
  int lane = threadIdx.x & 63;
  float s = 0.f;
#pragma unroll
  for (int it = 0; it < 4; ++it) {
    int i = it * 512 + lane * 8;
    bf16x8 w = *(const bf16x8*)&gwT[(size_t)j * INF + i];
    f32x4 m0 = *(const f32x4*)&mu[i];
    f32x4 m1 = *(const f32x4*)&mu[i + 4];
    s += (float)w[0] * m0[0] + (float)w[1] * m0[1] + (float)w[2] * m0[2] + (float)w[3] * m0[3];
    s += (float)w[4] * m1[0] + (float)w[5] * m1[1] + (float)w[6] * m1[2] + (float)w[7] * m1[3];
  }
  for (int off = 32; off; off >>= 1) s += __shfl_down(s, off);
  if (lane == 0) c[j] = gb[j] + s;
}

// ---------------- gate GEMM: tile 128x256 (one full stripe per block) ----
// 512 threads, 8 waves (2 row-groups x 4 col-groups), each wave 64x64,
// 32 MFMA per barrier-pair. Masked-A (128x64) computed ONCE per stripe
// instead of twice (mask VALU per FLOP halved vs 128x128).

__global__ __launch_bounds__(512) void gate_gemm(
    const bf16_t* __restrict__ xdb, const bf16_t* __restrict__ thrb,
    const bf16_t* __restrict__ gwT, const float* __restrict__ cj,
    bf16_t* __restrict__ g) {
  __shared__ bf16_t Al[128 * 64];   // 16 KB
  __shared__ bf16_t Bl[256 * 64];   // 32 KB
  int tid = threadIdx.x;
  int t0 = blockIdx.y * 128;
  int j0 = blockIdx.x * 256;
  int n = blockIdx.x;  // stripe == j-tile
  int lane = tid & 63;
  int wv = tid >> 6;
  int wr = (wv & 1) * 64;
  int wc = (wv >> 1) * 64;
  int m16 = lane & 15, q = lane >> 4;
  f32x4 acc[4][4] = {};
  const s16x8 absmask = {0x7FFF, 0x7FFF, 0x7FFF, 0x7FFF, 0x7FFF, 0x7FFF, 0x7FFF, 0x7FFF};
  for (int k0 = 0; k0 < INF; k0 += 64) {
    stage_async_t<256, 512>(gwT + (size_t)j0 * INF + k0, INF, Bl, tid);
    // masked A, branchless packed: active iff |a| > t  <=>  (t - |a|) < 0.
#pragma unroll
    for (int r = 0; r < 2; ++r) {
      int c = r * 512 + tid;
      int row = c >> 3;
      int slot = c & 7;
      int kq = slot ^ (row & 7);
      s16x8 a = *(const s16x8*)&xdb[(size_t)(t0 + row) * INF + k0 + kq * 8];
      s16x8 t = *(const s16x8*)&thrb[n * INF + k0 + kq * 8];
      s16x8 m = (s16x8)((t - (a & absmask)) >> 15);
      *(s16x8*)&Al[row * 64 + slot * 8] = a & m;
    }
    __syncthreads();
#pragma unroll
    for (int s = 0; s < 2; ++s) {
      bf16x8 af[4], bf[4];
#pragma unroll
      for (int mi = 0; mi < 4; ++mi) af[mi] = frag_ld64(Al, wr + mi * 16 + m16, s * 4 + q);
#pragma unroll
      for (int ni = 0; ni < 4; ++ni) bf[ni] = frag_ld64(Bl, wc + ni * 16 + m16, s * 4 + q);
#pragma unroll
      for (int mi = 0; mi < 4; ++mi)
#pragma unroll
        for (int ni = 0; ni < 4; ++ni)
          acc[mi][ni] = __builtin_amdgcn_mfma_f32_16x16x32_bf16(af[mi], bf[ni], acc[mi][ni], 0, 0, 0);
    }
    __syncthreads();
  }
#pragma unroll
  for (int mi = 0; mi < 4; ++mi)
#pragma unroll
    for (int ni = 0; ni < 4; ++ni) {
      int col = j0 + wc + ni * 16 + m16;
      float cadd = cj[col];
#pragma unroll
      for (int r = 0; r < 4; ++r) {
        int row = t0 + wr + mi * 16 + q * 4 + r;
        g[(size_t)row * JNF + col] = (bf16_t)(acc[mi][ni][r] + cadd);
      }
    }
}

// ---------------- up GEMM: tile 128x128, BK=64 (validated R4) ----------

__global__ __launch_bounds__(256) void up_gemm(
    const bf16_t* __restrict__ xb, const bf16_t* __restrict__ upT,
    const float* __restrict__ ub, const bf16_t* __restrict__ g,
    bf16_t* __restrict__ h) {
  __shared__ bf16_t Al[128 * 64];
  __shared__ bf16_t Bl[128 * 64];
  int tid = threadIdx.x;
  int t0 = blockIdx.y * 128;
  int j0 = blockIdx.x * 128;
  int lane = tid & 63;
  int wv = tid >> 6;
  int wr = (wv & 1) * 64;
  int wc = (wv >> 1) * 64;
  int m16 = lane & 15, q = lane >> 4;
  f32x4 acc[4][4] = {};
  for (int k0 = 0; k0 < INF; k0 += 64) {
    stage_async_t<128, 256>(xb + (size_t)t0 * INF + k0, INF, Al, tid);
    stage_async_t<128, 256>(upT + (size_t)j0 * INF + k0, INF, Bl, tid);
    __syncthreads();
#pragma unroll
    for (int s = 0; s < 2; ++s) {
      bf16x8 af[4], bf[4];
#pragma unroll
      for (int mi = 0; mi < 4; ++mi) af[mi] = frag_ld64(Al, wr + mi * 16 + m16, s * 4 + q);
#pragma unroll
      for (int ni = 0; ni < 4; ++ni) bf[ni] = frag_ld64(Bl, wc + ni * 16 + m16, s * 4 + q);
#pragma unroll
      for (int mi = 0; mi < 4; ++mi)
#pragma unroll
        for (int ni = 0; ni < 4; ++ni)
          acc[mi][ni] = __builtin_amdgcn_mfma_f32_16x16x32_bf16(af[mi], bf[ni], acc[mi][ni], 0, 0, 0);
    }
    __syncthreads();
  }
#pragma unroll
  for (int mi = 0; mi < 4; ++mi)
#pragma unroll
    for (int ni = 0; ni < 4; ++ni) {
      int col = j0 + wc + ni * 16 + m16;
      float bias = ub[col];
#pragma unroll
      for (int r = 0; r < 4; ++r) {
        int row = t0 + wr + mi * 16 + q * 4 + r;
        float upv = acc[mi][ni][r] + bias;
        float gv = (float)g[(size_t)row * JNF + col];
        float hv = (gv / (1.f + expf(-gv))) * upv;
        h[(size_t)row * JNF + col] = (bf16_t)hv;
      }
    }
}

// split-K partial: z-th K-chunk of 2048, no bias
__global__ __launch_bounds__(256) void down_gemm(
    const bf16_t* __restrict__ h, const bf16_t* __restrict__ dwb,
    float* __restrict__ part) {
  __shared__ bf16_t Al[128 * 64];
  __shared__ bf16_t Bl[128 * 64];
  int tid = threadIdx.x;
  int t0 = blockIdx.y * 128;
  int o0 = blockIdx.x * 128;
  int kz = blockIdx.z * 2048;
  int lane = tid & 63;
  int wv = tid >> 6;
  int wr = (wv & 1) * 64;
  int wc = (wv >> 1) * 64;
  int m16 = lane & 15, q = lane >> 4;
  f32x4 acc[4][4] = {};
  for (int k0 = kz; k0 < kz + 2048; k0 += 64) {
    stage_async_t<128, 256>(h + (size_t)t0 * JNF + k0, JNF, Al, tid);
    stage_async_t<128, 256>(dwb + (size_t)o0 * JNF + k0, JNF, Bl, tid);
    __syncthreads();
#pragma unroll
    for (int s = 0; s < 2; ++s) {
      bf16x8 af[4], bf[4];
#pragma unroll
      for (int mi = 0; mi < 4; ++mi) af[mi] = frag_ld64(Al, wr + mi * 16 + m16, s * 4 + q);
#pragma unroll
      for (int ni = 0; ni < 4; ++ni) bf[ni] = frag_ld64(Bl, wc + ni * 16 + m16, s * 4 + q);
#pragma unroll
      for (int mi = 0; mi < 4; ++mi)
#pragma unroll
        for (int ni = 0; ni < 4; ++ni)
          acc[mi][ni] = __builtin_amdgcn_mfma_f32_16x16x32_bf16(af[mi], bf[ni], acc[mi][ni], 0, 0, 0);
    }
    __syncthreads();
  }
  float* dst = part + (size_t)blockIdx.z * (TOKS * ONF);
#pragma unroll
  for (int mi = 0; mi < 4; ++mi)
#pragma unroll
    for (int ni = 0; ni < 4; ++ni) {
      int col = o0 + wc + ni * 16 + m16;
#pragma unroll
      for (int r = 0; r < 4; ++r) {
        int row = t0 + wr + mi * 16 + q * 4 + r;
        dst[(size_t)row * ONF + col] = acc[mi][ni][r];
      }
    }
}

__global__ __launch_bounds__(256) void down_reduce(
    const float* __restrict__ part, const float* __restrict__ db,
    float* __restrict__ y) {
  int idx = (blockIdx.x * 256 + threadIdx.x) * 4;
  f32x4 a = *(const f32x4*)&part[idx];
  f32x4 b = *(const f32x4*)&part[idx + 4194304];
  f32x4 c = *(const f32x4*)&part[idx + 2 * 4194304];
  f32x4 d = *(const f32x4*)&part[idx + 3 * 4194304];
  f32x4 bias = *(const f32x4*)&db[idx & (ONF - 1)];
  *(f32x4*)&y[idx] = a + b + c + d + bias;
}

// ---------------- launcher ----------------

extern "C" void kernel_launch(void* const* d_in, const int* in_sizes, int n_in,
                              void* d_out, int out_size, void* d_ws, size_t ws_size,
                              hipStream_t stream) {
  (void)in_sizes; (void)n_in; (void)out_size; (void)ws_size;
  const float* x   = (const float*)d_in[0];
  const float* gw  = (const float*)d_in[1];
  const float* gb  = (const float*)d_in[2];
  const float* gth = (const float*)d_in[3];
  const float* med = (const float*)d_in[4];
  const float* aad = (const float*)d_in[5];
  const float* uw  = (const float*)d_in[6];
  const float* ub  = (const float*)d_in[7];
  const float* dw  = (const float*)d_in[8];
  const float* db  = (const float*)d_in[9];

  float* out = (float*)d_out;
  float* y = out;                       // [2048,2048]
  float* dense = out + 4194304;         // [2048]
  float* active = dense + 2048;         // [2048]

  char* ws = (char*)d_ws;
  float*  mu   = (float*)(ws + 0);           //   8 KB
  float*  thr  = (float*)(ws + 8192);        // 256 KB (fp32, exact count)
  bf16_t* thrb = (bf16_t*)(ws + 270336);     // 128 KB (bf16 bits)
  float*  cj   = (float*)(ws + 401408);      //  32 KB
  bf16_t* xb   = (bf16_t*)(ws + 434176);     //   8 MB
  bf16_t* xdb  = (bf16_t*)(ws + 8822784);    //   8 MB
  bf16_t* gwT  = (bf16_t*)(ws + 17211392);   //  32 MB
  bf16_t* upT  = (bf16_t*)(ws + 50765824);   //  32 MB
  bf16_t* dwb  = (bf16_t*)(ws + 84320256);   //  32 MB
  bf16_t* hb   = (bf16_t*)(ws + 117874688);  //  32 MB
  float*  part = (float*)(ws + 151429120);   //  64 MB -> total ~218.5 MB
  bf16_t* gb16 = (bf16_t*)part;  // alias: g dead before down_gemm writes part

  float debiaser = (float)(1.0 / (1e-7 + (1.0 - pow(0.99, 1000.0))));

  prep_mu_thr<<<256, 256, 0, stream>>>(med, aad, gth, debiaser, mu, thr, thrb);
  prep_x_count<<<2048, 256, 0, stream>>>(x, mu, thr, xb, xdb, dense, active);
  transpose_cast_dual<<<dim3(256, 64, 2), 256, 0, stream>>>(gw, gwT, uw, upT);
  cast_bf16<<<8192, 256, 0, stream>>>(dw, dwb);
  c_from_gwT<<<2048, 256, 0, stream>>>(gwT, mu, gb, cj);
  gate_gemm<<<dim3(32, 16), 512, 0, stream>>>(xdb, thrb, gwT, cj, gb16);
  up_gemm<<<dim3(64, 16), 256, 0, stream>>>(xb, upT, ub, gb16, hb);
  down_gemm<<<dim3(16, 16, 4), 256, 0, stream>>>(hb, dwb, part);
  down_reduce<<<4096, 256, 0, stream>>>(part, db, y);
}